// Round 1
// baseline (2155.239 us; speedup 1.0000x reference)
//
#include <hip/hip_runtime.h>
#include <math.h>

// Problem constants
constexpr int kN = 4, kL = 512, kD = 128, kPD = 64, kH = 8, kC = 32, kNP = 8;

// Workspace offsets (in floats)
constexpr long OFF_FLAG = 0;                       // int flag at ws[0]
constexpr long OFF_RATIO = 16;                     // 4 floats
constexpr long OFF_QN  = 32;                       // N*L*256
constexpr long OFF_KN  = OFF_QN  + (long)kN * kL * 256;
constexpr long OFF_VN  = OFF_KN  + (long)kN * kL * 256;
constexpr long OFF_QP  = OFF_VN  + (long)kN * kL * 256;   // N*L*192 (global coords)
constexpr long OFF_KP  = OFF_QP  + (long)kN * kL * 192;
constexpr long OFF_VP  = OFF_KP  + (long)kN * kL * 192;
constexpr long OFF_QP2 = OFF_VP  + (long)kN * kL * 192;   // N*L*8
constexpr long OFF_KP2 = OFF_QP2 + (long)kN * kL * 8;
constexpr long OFF_AGG = OFF_KP2 + (long)kN * kL * 8;     // N*L*832

__device__ __forceinline__ bool mask_at(const void* p, long idx, int mt) {
  if (mt == 0) return ((const unsigned char*)p)[idx] != 0;
  if (mt == 1) return ((const int*)p)[idx] != 0;
  return ((const float*)p)[idx] != 0.0f;
}

// ---------------------------------------------------------------- detect mask dtype
__global__ void detect_mask_type_kernel(const unsigned int* __restrict__ m,
                                        int* __restrict__ flag) {
  if (threadIdx.x == 0) {
    int isFloat = 0, allLe1 = 1;
    for (int i = 0; i < 1024; ++i) {
      unsigned int w = m[i];
      if (w == 0x3F800000u) isFloat = 1;
      if (w > 1u) allLe1 = 0;
    }
    // float32 0/1 -> 2 ; int32 0/1 -> 1 ; packed bool bytes -> 0
    *flag = isFloat ? 2 : (allLe1 ? 1 : 0);
  }
}

// ---------------------------------------------------------------- per-batch mask ratio
__global__ __launch_bounds__(256) void mask_ratio_kernel(
    const void* __restrict__ intra, const void* __restrict__ inter,
    const int* __restrict__ flag, float* __restrict__ ratio) {
  __shared__ float red[256];
  const int n = blockIdx.x, tid = threadIdx.x;
  const int mt = *flag;
  const long base = (long)n * kL * kL;
  float si = 0.f, st = 0.f;
  for (long i = tid; i < (long)kL * kL; i += 256) {
    si += mask_at(intra, base + i, mt) ? 1.f : 0.f;
    st += mask_at(inter, base + i, mt) ? 1.f : 0.f;
  }
  red[tid] = si; __syncthreads();
  for (int s = 128; s > 0; s >>= 1) { if (tid < s) red[tid] += red[tid + s]; __syncthreads(); }
  const float sumI = red[0]; __syncthreads();
  red[tid] = st; __syncthreads();
  for (int s = 128; s > 0; s >>= 1) { if (tid < s) red[tid] += red[tid + s]; __syncthreads(); }
  if (tid == 0) ratio[n] = sumI / (sumI + red[0]);
}

// ---------------------------------------------------------------- projections
__global__ __launch_bounds__(256) void proj_kernel(
    const float* __restrict__ x, const float* __restrict__ R,
    const float* __restrict__ t,
    const float* __restrict__ Wq, const float* __restrict__ Wk,
    const float* __restrict__ Wv, const float* __restrict__ Wqp,
    const float* __restrict__ Wkp, const float* __restrict__ Wvp,
    float* __restrict__ qn, float* __restrict__ kn, float* __restrict__ vn,
    float* __restrict__ qp, float* __restrict__ kp, float* __restrict__ vp,
    float* __restrict__ qp2, float* __restrict__ kp2) {
  __shared__ float xs[8][128];
  __shared__ float plocal[8][192];
  __shared__ float pglob[8][192];
  __shared__ float Rl[8][9];
  __shared__ float tl[8][3];
  const int tid = threadIdx.x;
  const int bid = blockIdx.x;            // 256 blocks; 64 per batch, 8 rows each
  const int n = bid >> 6;
  const int l0 = (bid & 63) * 8;
  const long rowbase = (long)n * kL + l0;

  for (int f = tid * 4; f < 8 * 128; f += 256 * 4) {
    const float4 v = *(const float4*)&x[rowbase * 128 + f];
    *(float4*)&xs[f >> 7][f & 127] = v;
  }
  if (tid < 72) Rl[tid / 9][tid % 9] = R[rowbase * 9 + tid];
  if (tid >= 72 && tid < 96) { int q = tid - 72; tl[q / 3][q % 3] = t[rowbase * 3 + q]; }
  __syncthreads();

  // node projections (width 256)
  {
    const float* Ws[3] = {Wq, Wk, Wv};
    float* Os[3] = {qn, kn, vn};
    for (int wmat = 0; wmat < 3; ++wmat) {
      const float* W = Ws[wmat];
      float acc[8];
#pragma unroll
      for (int r = 0; r < 8; ++r) acc[r] = 0.f;
      for (int k = 0; k < 128; ++k) {
        const float w = W[k * 256 + tid];
#pragma unroll
        for (int r = 0; r < 8; ++r) acc[r] = fmaf(xs[r][k], w, acc[r]);
      }
#pragma unroll
      for (int r = 0; r < 8; ++r) Os[wmat][(rowbase + r) * 256 + tid] = acc[r];
    }
  }

  // point projections (width 192) + rigid transform + sum-of-squares
  {
    const float* Ws[3] = {Wqp, Wkp, Wvp};
    float* Os[3] = {qp, kp, vp};
    float* O2s[2] = {qp2, kp2};
    for (int wmat = 0; wmat < 3; ++wmat) {
      __syncthreads();
      if (tid < 192) {
        const float* W = Ws[wmat];
        float acc[8];
#pragma unroll
        for (int r = 0; r < 8; ++r) acc[r] = 0.f;
        for (int k = 0; k < 128; ++k) {
          const float w = W[k * 192 + tid];
#pragma unroll
          for (int r = 0; r < 8; ++r) acc[r] = fmaf(xs[r][k], w, acc[r]);
        }
#pragma unroll
        for (int r = 0; r < 8; ++r) plocal[r][tid] = acc[r];
      }
      __syncthreads();
      for (int task = tid; task < 512; task += 256) {
        const int r = task >> 6, hp = task & 63;
        const float px = plocal[r][hp * 3 + 0];
        const float py = plocal[r][hp * 3 + 1];
        const float pz = plocal[r][hp * 3 + 2];
#pragma unroll
        for (int i = 0; i < 3; ++i) {
          const float g = Rl[r][i * 3 + 0] * px + Rl[r][i * 3 + 1] * py +
                          Rl[r][i * 3 + 2] * pz + tl[r][i];
          pglob[r][hp * 3 + i] = g;
          Os[wmat][(rowbase + r) * 192 + hp * 3 + i] = g;
        }
      }
      __syncthreads();
      if (wmat < 2 && tid < 64) {
        const int r = tid >> 3, h = tid & 7;
        float s = 0.f;
#pragma unroll
        for (int j = 0; j < 24; ++j) {
          const float v = pglob[r][h * 24 + j];
          s = fmaf(v, v, s);
        }
        O2s[wmat][(rowbase + r) * 8 + h] = s;
      }
    }
  }
}

// ---------------------------------------------------------------- fused attention row
__global__ __launch_bounds__(256) void attn_kernel(
    const float* __restrict__ z, const void* __restrict__ intra,
    const void* __restrict__ inter, const int* __restrict__ flag,
    const float* __restrict__ ratio_arr,
    const float* __restrict__ R, const float* __restrict__ t,
    const float* __restrict__ qn, const float* __restrict__ kn,
    const float* __restrict__ vn, const float* __restrict__ qp,
    const float* __restrict__ kp, const float* __restrict__ vp,
    const float* __restrict__ qp2, const float* __restrict__ kp2,
    const float* __restrict__ Wpair, const float* __restrict__ spatial_coef,
    float* __restrict__ agg) {
  __shared__ float lg[512][8];      // logits -> alpha (16 KB)
  __shared__ float zbuf[64][68];    // z chunk, padded (17.4 KB)
  __shared__ float mI[512], mT[512];
  __shared__ float qn_l[8][36];     // padded
  __shared__ float qp_l[192];
  __shared__ float wp[64][8];
  __shared__ float red[2][256];
  __shared__ float smax[2][8], rmul[2][8];
  __shared__ float qp2_l[8], coef_l[8];
  __shared__ float fsbuf[192];
  __shared__ float Rl[9], tl[3];

  const int tid = threadIdx.x;
  const int bid = blockIdx.x;
  const int n = bid >> 9, l = bid & 511;
  const long row = (long)n * kL + l;
  const long nbase = (long)n * kL;
  const int mt = *flag;
  const float ratio = ratio_arr[n];

  // stage per-row constants
  qn_l[tid >> 5][tid & 31] = qn[row * 256 + tid];
  if (tid < 192) qp_l[tid] = qp[row * 192 + tid];
  if (tid < 8) {
    qp2_l[tid] = qp2[row * 8 + tid];
    const float g = logf(1.f + expf(spatial_coef[tid]));  // softplus
    coef_l[tid] = -g * sqrtf(2.f / (9.f * kNP)) * 0.5f;
  }
  for (int i = tid; i < 512; i += 256) wp[i >> 3][i & 7] = Wpair[i];
  if (tid < 9) Rl[tid] = R[row * 9 + tid];
  if (tid >= 16 && tid < 19) tl[tid - 16] = t[row * 3 + (tid - 16)];
  {
    const long mbase = row * kL;
    for (int m = tid; m < 512; m += 256) {
      mI[m] = mask_at(intra, mbase + m, mt) ? 1.f : 0.f;
      mT[m] = mask_at(inter, mbase + m, mt) ? 1.f : 0.f;
    }
  }
  __syncthreads();

  const float invsC = 0.17677669529663687f;  // 1/sqrt(32)
  const float invs3 = 0.5773502691896258f;   // sqrt(1/3)
  const int h = tid & 7, m0 = tid >> 3;
  const float coef = coef_l[h];
  const float q2h = qp2_l[h];

  // ---- phase 1: logits ----
  for (int mc = 0; mc < 8; ++mc) {
    __syncthreads();
    {
      const float* zrow = z + (row * kL + mc * 64) * 64;
      for (int f = tid * 4; f < 4096; f += 1024)
        *(float4*)&zbuf[f >> 6][f & 63] = *(const float4*)&zrow[f];
    }
    __syncthreads();
#pragma unroll
    for (int half = 0; half < 2; ++half) {
      const int mm = m0 + half * 32;
      const int mg = mc * 64 + mm;
      float dn = 0.f;
      const float* knp = &kn[(nbase + mg) * 256 + h * 32];
#pragma unroll
      for (int c4 = 0; c4 < 8; ++c4) {
        const float4 kv = *(const float4*)&knp[c4 * 4];
        dn = fmaf(qn_l[h][c4 * 4 + 0], kv.x, dn);
        dn = fmaf(qn_l[h][c4 * 4 + 1], kv.y, dn);
        dn = fmaf(qn_l[h][c4 * 4 + 2], kv.z, dn);
        dn = fmaf(qn_l[h][c4 * 4 + 3], kv.w, dn);
      }
      float dp = 0.f;
#pragma unroll 16
      for (int p = 0; p < 64; ++p) dp = fmaf(wp[p][h], zbuf[mm][p], dp);
      float ds = 0.f;
      const float* kpp = &kp[(nbase + mg) * 192 + h * 24];
      const float* qpp = &qp_l[h * 24];
#pragma unroll
      for (int j4 = 0; j4 < 6; ++j4) {
        const float4 kv = *(const float4*)&kpp[j4 * 4];
        ds = fmaf(qpp[j4 * 4 + 0], kv.x, ds);
        ds = fmaf(qpp[j4 * 4 + 1], kv.y, ds);
        ds = fmaf(qpp[j4 * 4 + 2], kv.z, ds);
        ds = fmaf(qpp[j4 * 4 + 3], kv.w, ds);
      }
      const float sumsq = q2h + kp2[(nbase + mg) * 8 + h] - 2.f * ds;
      lg[mg][h] = (dn * invsC + dp + sumsq * coef) * invs3;
    }
  }
  __syncthreads();

  // ---- phase 2: dual-mask softmax -> alpha in place ----
  const int h2 = tid & 7, j = tid >> 3;  // j in 0..31
  float mxI = -3.0e38f, mxT = -3.0e38f;
  for (int m = j; m < 512; m += 32) {
    const float v = lg[m][h2];
    if (mI[m] != 0.f && v > mxI) mxI = v;
    if (mT[m] != 0.f && v > mxT) mxT = v;
  }
  red[0][tid] = mxI; red[1][tid] = mxT;
  __syncthreads();
  for (int s = 16; s > 0; s >>= 1) {
    if (j < s) {
      red[0][tid] = fmaxf(red[0][tid], red[0][tid + s * 8]);
      red[1][tid] = fmaxf(red[1][tid], red[1][tid + s * 8]);
    }
    __syncthreads();
  }
  if (tid < 8) { smax[0][tid] = red[0][tid]; smax[1][tid] = red[1][tid]; }
  __syncthreads();
  const float mxIh = smax[0][h2], mxTh = smax[1][h2];
  float suI = 0.f, suT = 0.f;
  for (int m = j; m < 512; m += 32) {
    const float v = lg[m][h2];
    if (mI[m] != 0.f) suI += expf(v - mxIh);
    if (mT[m] != 0.f) suT += expf(v - mxTh);
  }
  red[0][tid] = suI; red[1][tid] = suT;
  __syncthreads();
  for (int s = 16; s > 0; s >>= 1) {
    if (j < s) {
      red[0][tid] += red[0][tid + s * 8];
      red[1][tid] += red[1][tid + s * 8];
    }
    __syncthreads();
  }
  if (tid < 8) {
    rmul[0][tid] = ratio / red[0][tid];
    rmul[1][tid] = (1.f - ratio) / red[1][tid];
  }
  __syncthreads();
  for (int idx = tid; idx < 4096; idx += 256) {
    const int m = idx >> 3, hh = idx & 7;
    const float v = lg[m][hh];
    float a = 0.f;
    if (mI[m] != 0.f) a = expf(v - smax[0][hh]) * rmul[0][hh];
    if (mT[m] != 0.f) a += expf(v - smax[1][hh]) * rmul[1][hh];
    lg[m][hh] = a;
  }
  __syncthreads();

  // ---- phase 3: aggregation ----
  const int hn = tid >> 5;                 // feat_node: h = tid/32, c = tid%32
  const int po = tid * 2;
  const int hpair = po >> 6, pp = po & 63; // feat_pair: 2 outputs per thread
  const int hs = tid / 24;                 // feat_spatial (tid<192): vp flat idx
  float accN = 0.f, accP0 = 0.f, accP1 = 0.f, accS = 0.f;
  for (int mc = 0; mc < 8; ++mc) {
    __syncthreads();
    {
      const float* zrow = z + (row * kL + mc * 64) * 64;
      for (int f = tid * 4; f < 4096; f += 1024)
        *(float4*)&zbuf[f >> 6][f & 63] = *(const float4*)&zrow[f];
    }
    __syncthreads();
#pragma unroll 4
    for (int mm = 0; mm < 64; ++mm) {
      const int mg = mc * 64 + mm;
      const float aN = lg[mg][hn];
      accN = fmaf(aN, vn[(nbase + mg) * 256 + tid], accN);
      const float aP = lg[mg][hpair];
      accP0 = fmaf(aP, zbuf[mm][pp], accP0);
      accP1 = fmaf(aP, zbuf[mm][pp + 1], accP1);
      if (tid < 192) accS = fmaf(lg[mg][hs], vp[(nbase + mg) * 192 + tid], accS);
    }
  }
  float* aggrow = &agg[row * 832];
  aggrow[tid] = accN;                 // feat_node [0,256)
  aggrow[256 + po] = accP0;           // feat_pair [256,768)
  aggrow[256 + po + 1] = accP1;
  if (tid < 192) fsbuf[tid] = accS;
  __syncthreads();
  if (tid < 64) {                     // feat_spatial [768,832)
    const float gx = fsbuf[tid * 3 + 0] - tl[0];
    const float gy = fsbuf[tid * 3 + 1] - tl[1];
    const float gz = fsbuf[tid * 3 + 2] - tl[2];
    float s = 0.f;
#pragma unroll
    for (int jj = 0; jj < 3; ++jj) {
      const float lv = Rl[0 + jj] * gx + Rl[3 + jj] * gy + Rl[6 + jj] * gz;
      s = fmaf(lv, lv, s);
    }
    aggrow[768 + tid] = sqrtf(s);
  }
}

// ---------------------------------------------------------------- transition / MLP
__device__ __forceinline__ float blk_sum128(float v, float* red, int tid) {
  red[tid] = v; __syncthreads();
  for (int s = 64; s > 0; s >>= 1) {
    if (tid < s) red[tid] += red[tid + s];
    __syncthreads();
  }
  const float r = red[0];
  __syncthreads();
  return r;
}

__global__ __launch_bounds__(128) void trans_kernel(
    const float* __restrict__ xg, const float* __restrict__ agg,
    const float* __restrict__ W1, const float* __restrict__ b1,
    const float* __restrict__ W2a, const float* __restrict__ b2a,
    const float* __restrict__ W2b, const float* __restrict__ b2b,
    const float* __restrict__ W2c, const float* __restrict__ b2c,
    const float* __restrict__ g1, const float* __restrict__ bb1,
    const float* __restrict__ g2, const float* __restrict__ bb2,
    float* __restrict__ out) {
  __shared__ float aggb[832];
  __shared__ float featb[128], hb1[128], hb2[128];
  __shared__ float red[128];
  const int tid = threadIdx.x;
  const long row = blockIdx.x;
  const float* arow = &agg[row * 832];
  for (int i = tid; i < 832; i += 128) aggb[i] = arow[i];
  __syncthreads();
  float acc = b1[tid];
  for (int a = 0; a < 832; ++a) acc = fmaf(aggb[a], W1[a * 128 + tid], acc);
  acc += xg[row * 128 + tid];
  const float mean = blk_sum128(acc, red, tid) * (1.f / 128.f);
  const float dv = acc - mean;
  const float var = blk_sum128(dv * dv, red, tid) * (1.f / 128.f);
  const float f = dv * rsqrtf(var + 1e-5f) * g1[tid] + bb1[tid];
  featb[tid] = f;
  __syncthreads();
  float a1 = b2a[tid];
  for (int k = 0; k < 128; ++k) a1 = fmaf(featb[k], W2a[k * 128 + tid], a1);
  hb1[tid] = fmaxf(a1, 0.f);
  __syncthreads();
  float a2 = b2b[tid];
  for (int k = 0; k < 128; ++k) a2 = fmaf(hb1[k], W2b[k * 128 + tid], a2);
  hb2[tid] = fmaxf(a2, 0.f);
  __syncthreads();
  float a3 = b2c[tid];
  for (int k = 0; k < 128; ++k) a3 = fmaf(hb2[k], W2c[k * 128 + tid], a3);
  const float res = f + a3;
  const float mean2 = blk_sum128(res, red, tid) * (1.f / 128.f);
  const float dv2 = res - mean2;
  const float var2 = blk_sum128(dv2 * dv2, red, tid) * (1.f / 128.f);
  out[row * 128 + tid] = dv2 * rsqrtf(var2 + 1e-5f) * g2[tid] + bb2[tid];
}

// ---------------------------------------------------------------- launch
extern "C" void kernel_launch(void* const* d_in, const int* in_sizes, int n_in,
                              void* d_out, int out_size, void* d_ws, size_t ws_size,
                              hipStream_t stream) {
  const float* R     = (const float*)d_in[0];
  const float* t     = (const float*)d_in[1];
  const float* x     = (const float*)d_in[2];
  const float* z     = (const float*)d_in[3];
  const void*  intra = d_in[4];
  const void*  inter = d_in[5];
  const float* Wq    = (const float*)d_in[6];
  const float* Wk    = (const float*)d_in[7];
  const float* Wv    = (const float*)d_in[8];
  const float* Wpair = (const float*)d_in[9];
  const float* sc    = (const float*)d_in[10];
  const float* Wqp   = (const float*)d_in[11];
  const float* Wkp   = (const float*)d_in[12];
  const float* Wvp   = (const float*)d_in[13];
  const float* W1    = (const float*)d_in[14];
  const float* b1    = (const float*)d_in[15];
  const float* W2a   = (const float*)d_in[16];
  const float* b2a   = (const float*)d_in[17];
  const float* W2b   = (const float*)d_in[18];
  const float* b2b   = (const float*)d_in[19];
  const float* W2c   = (const float*)d_in[20];
  const float* b2c   = (const float*)d_in[21];
  const float* ln1g  = (const float*)d_in[22];
  const float* ln1b  = (const float*)d_in[23];
  const float* ln2g  = (const float*)d_in[24];
  const float* ln2b  = (const float*)d_in[25];
  float* ws = (float*)d_ws;
  float* out = (float*)d_out;

  int* flag = (int*)ws;
  float* ratio = ws + OFF_RATIO;
  float* qn = ws + OFF_QN;  float* kn = ws + OFF_KN;  float* vn = ws + OFF_VN;
  float* qp = ws + OFF_QP;  float* kp = ws + OFF_KP;  float* vp = ws + OFF_VP;
  float* qp2 = ws + OFF_QP2; float* kp2 = ws + OFF_KP2;
  float* agg = ws + OFF_AGG;

  detect_mask_type_kernel<<<1, 64, 0, stream>>>((const unsigned int*)intra, flag);
  mask_ratio_kernel<<<kN, 256, 0, stream>>>(intra, inter, flag, ratio);
  proj_kernel<<<kN * kL / 8, 256, 0, stream>>>(x, R, t, Wq, Wk, Wv, Wqp, Wkp, Wvp,
                                               qn, kn, vn, qp, kp, vp, qp2, kp2);
  attn_kernel<<<kN * kL, 256, 0, stream>>>(z, intra, inter, flag, ratio, R, t,
                                           qn, kn, vn, qp, kp, vp, qp2, kp2,
                                           Wpair, sc, agg);
  trans_kernel<<<kN * kL, 128, 0, stream>>>(x, agg, W1, b1, W2a, b2a, W2b, b2b,
                                            W2c, b2c, ln1g, ln1b, ln2g, ln2b, out);
}

// Round 2
// 1205.328 us; speedup vs baseline: 1.7881x; 1.7881x over previous
//
#include <hip/hip_runtime.h>
#include <math.h>

// Problem constants
constexpr int kN = 4, kL = 512, kD = 128, kPD = 64, kH = 8, kC = 32, kNP = 8;

// Workspace offsets (in floats)
constexpr long OFF_FLAG = 0;                       // int flag at ws[0]
constexpr long OFF_RATIO = 16;                     // 4 floats
constexpr long OFF_SUMS = 24;                      // 8 floats (per-batch intra/inter counts)
constexpr long OFF_QN  = 32;                       // N*L*256
constexpr long OFF_KN  = OFF_QN  + (long)kN * kL * 256;
constexpr long OFF_VN  = OFF_KN  + (long)kN * kL * 256;
constexpr long OFF_QP  = OFF_VN  + (long)kN * kL * 256;   // N*L*192 (global coords)
constexpr long OFF_KP  = OFF_QP  + (long)kN * kL * 192;
constexpr long OFF_VP  = OFF_KP  + (long)kN * kL * 192;
constexpr long OFF_QP2 = OFF_VP  + (long)kN * kL * 192;   // N*L*8
constexpr long OFF_KP2 = OFF_QP2 + (long)kN * kL * 8;
constexpr long OFF_AGG = OFF_KP2 + (long)kN * kL * 8;     // N*L*832

__device__ __forceinline__ bool mask_at(const void* p, long idx, int mt) {
  if (mt == 0) return ((const unsigned char*)p)[idx] != 0;
  if (mt == 1) return ((const int*)p)[idx] != 0;
  return ((const float*)p)[idx] != 0.0f;
}

// ---------------------------------------------------------------- detect mask dtype
__global__ __launch_bounds__(256) void detect_mask_type_kernel(
    const unsigned int* __restrict__ m, int* __restrict__ flag) {
  __shared__ int sFloat, sGt1;
  if (threadIdx.x == 0) { sFloat = 0; sGt1 = 0; }
  __syncthreads();
  int isFloat = 0, gt1 = 0;
#pragma unroll
  for (int i = 0; i < 4; ++i) {
    const unsigned int w = m[threadIdx.x + i * 256];
    if (w == 0x3F800000u) isFloat = 1;
    if (w > 1u) gt1 = 1;
  }
  if (isFloat) atomicOr(&sFloat, 1);
  if (gt1) atomicOr(&sGt1, 1);
  __syncthreads();
  if (threadIdx.x == 0) {
    // float32 0/1 -> 2 ; packed bool bytes (words >1, not 1.0f) -> 0 ; int32 0/1 -> 1
    *flag = sFloat ? 2 : (sGt1 ? 0 : 1);
  }
}

// ---------------------------------------------------------------- mask ratio (3 stages)
__global__ void zero_sums_kernel(float* __restrict__ sums) {
  if (threadIdx.x < 8) sums[threadIdx.x] = 0.f;
}

__global__ __launch_bounds__(256) void mask_ratio_partial_kernel(
    const void* __restrict__ intra, const void* __restrict__ inter,
    const int* __restrict__ flag, float* __restrict__ sums) {
  __shared__ float red[2][256];
  const int tid = threadIdx.x;
  const int bid = blockIdx.x;     // 256 blocks: 64 per batch
  const int n = bid >> 6;
  const int mt = *flag;
  const long base = (long)n * kL * kL + (long)(bid & 63) * 4096;
  float si = 0.f, st = 0.f;
  for (int i = tid; i < 4096; i += 256) {
    si += mask_at(intra, base + i, mt) ? 1.f : 0.f;
    st += mask_at(inter, base + i, mt) ? 1.f : 0.f;
  }
  red[0][tid] = si; red[1][tid] = st;
  __syncthreads();
  for (int s = 128; s > 0; s >>= 1) {
    if (tid < s) { red[0][tid] += red[0][tid + s]; red[1][tid] += red[1][tid + s]; }
    __syncthreads();
  }
  if (tid == 0) {
    atomicAdd(&sums[n * 2 + 0], red[0][0]);
    atomicAdd(&sums[n * 2 + 1], red[1][0]);
  }
}

__global__ void mask_ratio_final_kernel(const float* __restrict__ sums,
                                        float* __restrict__ ratio) {
  const int n = threadIdx.x;
  if (n < kN) ratio[n] = sums[n * 2] / (sums[n * 2] + sums[n * 2 + 1]);
}

// ---------------------------------------------------------------- projections
__global__ __launch_bounds__(256) void proj_kernel(
    const float* __restrict__ x, const float* __restrict__ R,
    const float* __restrict__ t,
    const float* __restrict__ Wq, const float* __restrict__ Wk,
    const float* __restrict__ Wv, const float* __restrict__ Wqp,
    const float* __restrict__ Wkp, const float* __restrict__ Wvp,
    float* __restrict__ qn, float* __restrict__ kn, float* __restrict__ vn,
    float* __restrict__ qp, float* __restrict__ kp, float* __restrict__ vp,
    float* __restrict__ qp2, float* __restrict__ kp2) {
  __shared__ float xs[8][128];
  __shared__ float plocal[8][192];
  __shared__ float pglob[8][192];
  __shared__ float Rl[8][9];
  __shared__ float tl[8][3];
  const int tid = threadIdx.x;
  const int bid = blockIdx.x;            // 256 blocks; 64 per batch, 8 rows each
  const int n = bid >> 6;
  const int l0 = (bid & 63) * 8;
  const long rowbase = (long)n * kL + l0;

  for (int f = tid * 4; f < 8 * 128; f += 256 * 4) {
    const float4 v = *(const float4*)&x[rowbase * 128 + f];
    *(float4*)&xs[f >> 7][f & 127] = v;
  }
  if (tid < 72) Rl[tid / 9][tid % 9] = R[rowbase * 9 + tid];
  if (tid >= 72 && tid < 96) { int q = tid - 72; tl[q / 3][q % 3] = t[rowbase * 3 + q]; }
  __syncthreads();

  // node projections (width 256)
  {
    const float* Ws[3] = {Wq, Wk, Wv};
    float* Os[3] = {qn, kn, vn};
    for (int wmat = 0; wmat < 3; ++wmat) {
      const float* W = Ws[wmat];
      float acc[8];
#pragma unroll
      for (int r = 0; r < 8; ++r) acc[r] = 0.f;
      for (int k = 0; k < 128; ++k) {
        const float w = W[k * 256 + tid];
#pragma unroll
        for (int r = 0; r < 8; ++r) acc[r] = fmaf(xs[r][k], w, acc[r]);
      }
#pragma unroll
      for (int r = 0; r < 8; ++r) Os[wmat][(rowbase + r) * 256 + tid] = acc[r];
    }
  }

  // point projections (width 192) + rigid transform + sum-of-squares
  {
    const float* Ws[3] = {Wqp, Wkp, Wvp};
    float* Os[3] = {qp, kp, vp};
    float* O2s[2] = {qp2, kp2};
    for (int wmat = 0; wmat < 3; ++wmat) {
      __syncthreads();
      if (tid < 192) {
        const float* W = Ws[wmat];
        float acc[8];
#pragma unroll
        for (int r = 0; r < 8; ++r) acc[r] = 0.f;
        for (int k = 0; k < 128; ++k) {
          const float w = W[k * 192 + tid];
#pragma unroll
          for (int r = 0; r < 8; ++r) acc[r] = fmaf(xs[r][k], w, acc[r]);
        }
#pragma unroll
        for (int r = 0; r < 8; ++r) plocal[r][tid] = acc[r];
      }
      __syncthreads();
      for (int task = tid; task < 512; task += 256) {
        const int r = task >> 6, hp = task & 63;
        const float px = plocal[r][hp * 3 + 0];
        const float py = plocal[r][hp * 3 + 1];
        const float pz = plocal[r][hp * 3 + 2];
#pragma unroll
        for (int i = 0; i < 3; ++i) {
          const float g = Rl[r][i * 3 + 0] * px + Rl[r][i * 3 + 1] * py +
                          Rl[r][i * 3 + 2] * pz + tl[r][i];
          pglob[r][hp * 3 + i] = g;
          Os[wmat][(rowbase + r) * 192 + hp * 3 + i] = g;
        }
      }
      __syncthreads();
      if (wmat < 2 && tid < 64) {
        const int r = tid >> 3, h = tid & 7;
        float s = 0.f;
#pragma unroll
        for (int j = 0; j < 24; ++j) {
          const float v = pglob[r][h * 24 + j];
          s = fmaf(v, v, s);
        }
        O2s[wmat][(rowbase + r) * 8 + h] = s;
      }
    }
  }
}

// ---------------------------------------------------------------- fused attention row
__global__ __launch_bounds__(256) void attn_kernel(
    const float* __restrict__ z, const void* __restrict__ intra,
    const void* __restrict__ inter, const int* __restrict__ flag,
    const float* __restrict__ ratio_arr,
    const float* __restrict__ R, const float* __restrict__ t,
    const float* __restrict__ qn, const float* __restrict__ kn,
    const float* __restrict__ vn, const float* __restrict__ qp,
    const float* __restrict__ kp, const float* __restrict__ vp,
    const float* __restrict__ qp2, const float* __restrict__ kp2,
    const float* __restrict__ Wpair, const float* __restrict__ spatial_coef,
    float* __restrict__ agg) {
  __shared__ float lg[512][8];      // logits -> alpha (16 KB)
  __shared__ float zbuf[64][68];    // z chunk, padded (17.4 KB)
  __shared__ float mI[512], mT[512];
  __shared__ float qn_l[8][36];     // padded
  __shared__ float qp_l[192];
  __shared__ float wp[64][8];
  __shared__ float red[2][256];
  __shared__ float smax[2][8], rmul[2][8];
  __shared__ float qp2_l[8], coef_l[8];
  __shared__ float fsbuf[192];
  __shared__ float Rl[9], tl[3];

  const int tid = threadIdx.x;
  const int bid = blockIdx.x;
  const int n = bid >> 9, l = bid & 511;
  const long row = (long)n * kL + l;
  const long nbase = (long)n * kL;
  const int mt = *flag;
  const float ratio = ratio_arr[n];

  // stage per-row constants
  qn_l[tid >> 5][tid & 31] = qn[row * 256 + tid];
  if (tid < 192) qp_l[tid] = qp[row * 192 + tid];
  if (tid < 8) {
    qp2_l[tid] = qp2[row * 8 + tid];
    const float g = logf(1.f + expf(spatial_coef[tid]));  // softplus
    coef_l[tid] = -g * sqrtf(2.f / (9.f * kNP)) * 0.5f;
  }
  for (int i = tid; i < 512; i += 256) wp[i >> 3][i & 7] = Wpair[i];
  if (tid < 9) Rl[tid] = R[row * 9 + tid];
  if (tid >= 16 && tid < 19) tl[tid - 16] = t[row * 3 + (tid - 16)];
  {
    const long mbase = row * kL;
    for (int m = tid; m < 512; m += 256) {
      mI[m] = mask_at(intra, mbase + m, mt) ? 1.f : 0.f;
      mT[m] = mask_at(inter, mbase + m, mt) ? 1.f : 0.f;
    }
  }
  __syncthreads();

  const float invsC = 0.17677669529663687f;  // 1/sqrt(32)
  const float invs3 = 0.5773502691896258f;   // sqrt(1/3)
  const int h = tid & 7, m0 = tid >> 3;
  const float coef = coef_l[h];
  const float q2h = qp2_l[h];

  // ---- phase 1: logits ----
  for (int mc = 0; mc < 8; ++mc) {
    __syncthreads();
    {
      const float* zrow = z + (row * kL + mc * 64) * 64;
      for (int f = tid * 4; f < 4096; f += 1024)
        *(float4*)&zbuf[f >> 6][f & 63] = *(const float4*)&zrow[f];
    }
    __syncthreads();
#pragma unroll
    for (int half = 0; half < 2; ++half) {
      const int mm = m0 + half * 32;
      const int mg = mc * 64 + mm;
      float dn = 0.f;
      const float* knp = &kn[(nbase + mg) * 256 + h * 32];
#pragma unroll
      for (int c4 = 0; c4 < 8; ++c4) {
        const float4 kv = *(const float4*)&knp[c4 * 4];
        dn = fmaf(qn_l[h][c4 * 4 + 0], kv.x, dn);
        dn = fmaf(qn_l[h][c4 * 4 + 1], kv.y, dn);
        dn = fmaf(qn_l[h][c4 * 4 + 2], kv.z, dn);
        dn = fmaf(qn_l[h][c4 * 4 + 3], kv.w, dn);
      }
      float dp = 0.f;
#pragma unroll 16
      for (int p = 0; p < 64; ++p) dp = fmaf(wp[p][h], zbuf[mm][p], dp);
      float ds = 0.f;
      const float* kpp = &kp[(nbase + mg) * 192 + h * 24];
      const float* qpp = &qp_l[h * 24];
#pragma unroll
      for (int j4 = 0; j4 < 6; ++j4) {
        const float4 kv = *(const float4*)&kpp[j4 * 4];
        ds = fmaf(qpp[j4 * 4 + 0], kv.x, ds);
        ds = fmaf(qpp[j4 * 4 + 1], kv.y, ds);
        ds = fmaf(qpp[j4 * 4 + 2], kv.z, ds);
        ds = fmaf(qpp[j4 * 4 + 3], kv.w, ds);
      }
      const float sumsq = q2h + kp2[(nbase + mg) * 8 + h] - 2.f * ds;
      lg[mg][h] = (dn * invsC + dp + sumsq * coef) * invs3;
    }
  }
  __syncthreads();

  // ---- phase 2: dual-mask softmax -> alpha in place ----
  const int h2 = tid & 7, j = tid >> 3;  // j in 0..31
  float mxI = -3.0e38f, mxT = -3.0e38f;
  for (int m = j; m < 512; m += 32) {
    const float v = lg[m][h2];
    if (mI[m] != 0.f && v > mxI) mxI = v;
    if (mT[m] != 0.f && v > mxT) mxT = v;
  }
  red[0][tid] = mxI; red[1][tid] = mxT;
  __syncthreads();
  for (int s = 16; s > 0; s >>= 1) {
    if (j < s) {
      red[0][tid] = fmaxf(red[0][tid], red[0][tid + s * 8]);
      red[1][tid] = fmaxf(red[1][tid], red[1][tid + s * 8]);
    }
    __syncthreads();
  }
  if (tid < 8) { smax[0][tid] = red[0][tid]; smax[1][tid] = red[1][tid]; }
  __syncthreads();
  const float mxIh = smax[0][h2], mxTh = smax[1][h2];
  float suI = 0.f, suT = 0.f;
  for (int m = j; m < 512; m += 32) {
    const float v = lg[m][h2];
    if (mI[m] != 0.f) suI += expf(v - mxIh);
    if (mT[m] != 0.f) suT += expf(v - mxTh);
  }
  red[0][tid] = suI; red[1][tid] = suT;
  __syncthreads();
  for (int s = 16; s > 0; s >>= 1) {
    if (j < s) {
      red[0][tid] += red[0][tid + s * 8];
      red[1][tid] += red[1][tid + s * 8];
    }
    __syncthreads();
  }
  if (tid < 8) {
    rmul[0][tid] = ratio / red[0][tid];
    rmul[1][tid] = (1.f - ratio) / red[1][tid];
  }
  __syncthreads();
  for (int idx = tid; idx < 4096; idx += 256) {
    const int m = idx >> 3, hh = idx & 7;
    const float v = lg[m][hh];
    float a = 0.f;
    if (mI[m] != 0.f) a = expf(v - smax[0][hh]) * rmul[0][hh];
    if (mT[m] != 0.f) a += expf(v - smax[1][hh]) * rmul[1][hh];
    lg[m][hh] = a;
  }
  __syncthreads();

  // ---- phase 3: aggregation ----
  const int hn = tid >> 5;                 // feat_node: h = tid/32, c = tid%32
  const int po = tid * 2;
  const int hpair = po >> 6, pp = po & 63; // feat_pair: 2 outputs per thread
  const int hs = tid / 24;                 // feat_spatial (tid<192): vp flat idx
  float accN = 0.f, accP0 = 0.f, accP1 = 0.f, accS = 0.f;
  for (int mc = 0; mc < 8; ++mc) {
    __syncthreads();
    {
      const float* zrow = z + (row * kL + mc * 64) * 64;
      for (int f = tid * 4; f < 4096; f += 1024)
        *(float4*)&zbuf[f >> 6][f & 63] = *(const float4*)&zrow[f];
    }
    __syncthreads();
#pragma unroll 4
    for (int mm = 0; mm < 64; ++mm) {
      const int mg = mc * 64 + mm;
      const float aN = lg[mg][hn];
      accN = fmaf(aN, vn[(nbase + mg) * 256 + tid], accN);
      const float aP = lg[mg][hpair];
      accP0 = fmaf(aP, zbuf[mm][pp], accP0);
      accP1 = fmaf(aP, zbuf[mm][pp + 1], accP1);
      if (tid < 192) accS = fmaf(lg[mg][hs], vp[(nbase + mg) * 192 + tid], accS);
    }
  }
  float* aggrow = &agg[row * 832];
  aggrow[tid] = accN;                 // feat_node [0,256)
  aggrow[256 + po] = accP0;           // feat_pair [256,768)
  aggrow[256 + po + 1] = accP1;
  if (tid < 192) fsbuf[tid] = accS;
  __syncthreads();
  if (tid < 64) {                     // feat_spatial [768,832)
    const float gx = fsbuf[tid * 3 + 0] - tl[0];
    const float gy = fsbuf[tid * 3 + 1] - tl[1];
    const float gz = fsbuf[tid * 3 + 2] - tl[2];
    float s = 0.f;
#pragma unroll
    for (int jj = 0; jj < 3; ++jj) {
      const float lv = Rl[0 + jj] * gx + Rl[3 + jj] * gy + Rl[6 + jj] * gz;
      s = fmaf(lv, lv, s);
    }
    aggrow[768 + tid] = sqrtf(s);
  }
}

// ---------------------------------------------------------------- transition / MLP
__device__ __forceinline__ float blk_sum128(float v, float* red, int tid) {
  red[tid] = v; __syncthreads();
  for (int s = 64; s > 0; s >>= 1) {
    if (tid < s) red[tid] += red[tid + s];
    __syncthreads();
  }
  const float r = red[0];
  __syncthreads();
  return r;
}

__global__ __launch_bounds__(128) void trans_kernel(
    const float* __restrict__ xg, const float* __restrict__ agg,
    const float* __restrict__ W1, const float* __restrict__ b1,
    const float* __restrict__ W2a, const float* __restrict__ b2a,
    const float* __restrict__ W2b, const float* __restrict__ b2b,
    const float* __restrict__ W2c, const float* __restrict__ b2c,
    const float* __restrict__ g1, const float* __restrict__ bb1,
    const float* __restrict__ g2, const float* __restrict__ bb2,
    float* __restrict__ out) {
  __shared__ float aggb[832];
  __shared__ float featb[128], hb1[128], hb2[128];
  __shared__ float red[128];
  const int tid = threadIdx.x;
  const long row = blockIdx.x;
  const float* arow = &agg[row * 832];
  for (int i = tid; i < 832; i += 128) aggb[i] = arow[i];
  __syncthreads();
  float acc = b1[tid];
  for (int a = 0; a < 832; ++a) acc = fmaf(aggb[a], W1[a * 128 + tid], acc);
  acc += xg[row * 128 + tid];
  const float mean = blk_sum128(acc, red, tid) * (1.f / 128.f);
  const float dv = acc - mean;
  const float var = blk_sum128(dv * dv, red, tid) * (1.f / 128.f);
  const float f = dv * rsqrtf(var + 1e-5f) * g1[tid] + bb1[tid];
  featb[tid] = f;
  __syncthreads();
  float a1 = b2a[tid];
  for (int k = 0; k < 128; ++k) a1 = fmaf(featb[k], W2a[k * 128 + tid], a1);
  hb1[tid] = fmaxf(a1, 0.f);
  __syncthreads();
  float a2 = b2b[tid];
  for (int k = 0; k < 128; ++k) a2 = fmaf(hb1[k], W2b[k * 128 + tid], a2);
  hb2[tid] = fmaxf(a2, 0.f);
  __syncthreads();
  float a3 = b2c[tid];
  for (int k = 0; k < 128; ++k) a3 = fmaf(hb2[k], W2c[k * 128 + tid], a3);
  const float res = f + a3;
  const float mean2 = blk_sum128(res, red, tid) * (1.f / 128.f);
  const float dv2 = res - mean2;
  const float var2 = blk_sum128(dv2 * dv2, red, tid) * (1.f / 128.f);
  out[row * 128 + tid] = dv2 * rsqrtf(var2 + 1e-5f) * g2[tid] + bb2[tid];
}

// ---------------------------------------------------------------- launch
extern "C" void kernel_launch(void* const* d_in, const int* in_sizes, int n_in,
                              void* d_out, int out_size, void* d_ws, size_t ws_size,
                              hipStream_t stream) {
  const float* R     = (const float*)d_in[0];
  const float* t     = (const float*)d_in[1];
  const float* x     = (const float*)d_in[2];
  const float* z     = (const float*)d_in[3];
  const void*  intra = d_in[4];
  const void*  inter = d_in[5];
  const float* Wq    = (const float*)d_in[6];
  const float* Wk    = (const float*)d_in[7];
  const float* Wv    = (const float*)d_in[8];
  const float* Wpair = (const float*)d_in[9];
  const float* sc    = (const float*)d_in[10];
  const float* Wqp   = (const float*)d_in[11];
  const float* Wkp   = (const float*)d_in[12];
  const float* Wvp   = (const float*)d_in[13];
  const float* W1    = (const float*)d_in[14];
  const float* b1    = (const float*)d_in[15];
  const float* W2a   = (const float*)d_in[16];
  const float* b2a   = (const float*)d_in[17];
  const float* W2b   = (const float*)d_in[18];
  const float* b2b   = (const float*)d_in[19];
  const float* W2c   = (const float*)d_in[20];
  const float* b2c   = (const float*)d_in[21];
  const float* ln1g  = (const float*)d_in[22];
  const float* ln1b  = (const float*)d_in[23];
  const float* ln2g  = (const float*)d_in[24];
  const float* ln2b  = (const float*)d_in[25];
  float* ws = (float*)d_ws;
  float* out = (float*)d_out;

  int* flag = (int*)ws;
  float* ratio = ws + OFF_RATIO;
  float* sums = ws + OFF_SUMS;
  float* qn = ws + OFF_QN;  float* kn = ws + OFF_KN;  float* vn = ws + OFF_VN;
  float* qp = ws + OFF_QP;  float* kp = ws + OFF_KP;  float* vp = ws + OFF_VP;
  float* qp2 = ws + OFF_QP2; float* kp2 = ws + OFF_KP2;
  float* agg = ws + OFF_AGG;

  detect_mask_type_kernel<<<1, 256, 0, stream>>>((const unsigned int*)intra, flag);
  zero_sums_kernel<<<1, 64, 0, stream>>>(sums);
  mask_ratio_partial_kernel<<<256, 256, 0, stream>>>(intra, inter, flag, sums);
  mask_ratio_final_kernel<<<1, 64, 0, stream>>>(sums, ratio);
  proj_kernel<<<kN * kL / 8, 256, 0, stream>>>(x, R, t, Wq, Wk, Wv, Wqp, Wkp, Wvp,
                                               qn, kn, vn, qp, kp, vp, qp2, kp2);
  attn_kernel<<<kN * kL, 256, 0, stream>>>(z, intra, inter, flag, ratio, R, t,
                                           qn, kn, vn, qp, kp, vp, qp2, kp2,
                                           Wpair, sc, agg);
  trans_kernel<<<kN * kL, 128, 0, stream>>>(x, agg, W1, b1, W2a, b2a, W2b, b2b,
                                            W2c, b2c, ln1g, ln1b, ln2g, ln2b, out);
}

// Round 7
// 1103.794 us; speedup vs baseline: 1.9526x; 1.0920x over previous
//
#include <hip/hip_runtime.h>
#include <math.h>

// Problem constants
constexpr int kN = 4, kL = 512, kD = 128, kPD = 64, kH = 8, kC = 32, kNP = 8;

// Workspace offsets (in floats)
constexpr long OFF_FLAG = 0;                       // int flag at ws[0]
constexpr long OFF_RATIO = 16;                     // 4 floats
constexpr long OFF_SUMS = 24;                      // 8 floats
constexpr long OFF_QN  = 32;                       // N*L*256
constexpr long OFF_KN  = OFF_QN  + (long)kN * kL * 256;
constexpr long OFF_VN  = OFF_KN  + (long)kN * kL * 256;
constexpr long OFF_QP  = OFF_VN  + (long)kN * kL * 256;   // N*L*192 (global coords)
constexpr long OFF_KP  = OFF_QP  + (long)kN * kL * 192;
constexpr long OFF_VP  = OFF_KP  + (long)kN * kL * 192;
constexpr long OFF_QP2 = OFF_VP  + (long)kN * kL * 192;   // N*L*8
constexpr long OFF_KP2 = OFF_QP2 + (long)kN * kL * 8;
constexpr long OFF_AGG = OFF_KP2 + (long)kN * kL * 8;     // N*L*832
constexpr long OFF_ZW  = OFF_AGG + (long)kN * kL * 832;   // N*L*L*8 (z @ Wpair)

#define E4(v,kk) ((kk)==0?(v).x:((kk)==1?(v).y:((kk)==2?(v).z:(v).w)))

__device__ __forceinline__ bool mask_at(const void* p, long idx, int mt) {
  if (mt == 0) return ((const unsigned char*)p)[idx] != 0;
  if (mt == 1) return ((const int*)p)[idx] != 0;
  return ((const float*)p)[idx] != 0.0f;
}

// ---------------------------------------------------------------- detect mask dtype
__global__ __launch_bounds__(256) void detect_mask_type_kernel(
    const unsigned int* __restrict__ m, int* __restrict__ flag) {
  __shared__ int sFloat, sGt1;
  if (threadIdx.x == 0) { sFloat = 0; sGt1 = 0; }
  __syncthreads();
  int isFloat = 0, gt1 = 0;
#pragma unroll
  for (int i = 0; i < 4; ++i) {
    const unsigned int w = m[threadIdx.x + i * 256];
    if (w == 0x3F800000u) isFloat = 1;
    if (w > 1u) gt1 = 1;
  }
  if (isFloat) atomicOr(&sFloat, 1);
  if (gt1) atomicOr(&sGt1, 1);
  __syncthreads();
  if (threadIdx.x == 0) *flag = sFloat ? 2 : (sGt1 ? 0 : 1);
}

// ---------------------------------------------------------------- mask ratio (3 stages)
__global__ void zero_sums_kernel(float* __restrict__ sums) {
  if (threadIdx.x < 8) sums[threadIdx.x] = 0.f;
}

__global__ __launch_bounds__(256) void mask_ratio_partial_kernel(
    const void* __restrict__ intra, const void* __restrict__ inter,
    const int* __restrict__ flag, float* __restrict__ sums) {
  __shared__ float red[2][256];
  const int tid = threadIdx.x;
  const int bid = blockIdx.x;
  const int n = bid >> 6;
  const int mt = *flag;
  const long base = (long)n * kL * kL + (long)(bid & 63) * 4096;
  float si = 0.f, st = 0.f;
  for (int i = tid; i < 4096; i += 256) {
    si += mask_at(intra, base + i, mt) ? 1.f : 0.f;
    st += mask_at(inter, base + i, mt) ? 1.f : 0.f;
  }
  red[0][tid] = si; red[1][tid] = st;
  __syncthreads();
  for (int s = 128; s > 0; s >>= 1) {
    if (tid < s) { red[0][tid] += red[0][tid + s]; red[1][tid] += red[1][tid + s]; }
    __syncthreads();
  }
  if (tid == 0) {
    atomicAdd(&sums[n * 2 + 0], red[0][0]);
    atomicAdd(&sums[n * 2 + 1], red[1][0]);
  }
}

__global__ void mask_ratio_final_kernel(const float* __restrict__ sums,
                                        float* __restrict__ ratio) {
  const int n = threadIdx.x;
  if (n < kN) ratio[n] = sums[n * 2] / (sums[n * 2] + sums[n * 2 + 1]);
}

// ---------------------------------------------------------------- projections
__global__ __launch_bounds__(256) void proj_kernel(
    const float* __restrict__ x, const float* __restrict__ R,
    const float* __restrict__ t,
    const float* __restrict__ Wq, const float* __restrict__ Wk,
    const float* __restrict__ Wv, const float* __restrict__ Wqp,
    const float* __restrict__ Wkp, const float* __restrict__ Wvp,
    float* __restrict__ qn, float* __restrict__ kn, float* __restrict__ vn,
    float* __restrict__ qp, float* __restrict__ kp, float* __restrict__ vp,
    float* __restrict__ qp2, float* __restrict__ kp2) {
  __shared__ float xs[8][128];
  __shared__ float plocal[8][192];
  __shared__ float pglob[8][192];
  __shared__ float Rl[8][9];
  __shared__ float tl[8][3];
  const int tid = threadIdx.x;
  const int bid = blockIdx.x;
  const int n = bid >> 6;
  const int l0 = (bid & 63) * 8;
  const long rowbase = (long)n * kL + l0;

  for (int f = tid * 4; f < 8 * 128; f += 256 * 4) {
    const float4 v = *(const float4*)&x[rowbase * 128 + f];
    *(float4*)&xs[f >> 7][f & 127] = v;
  }
  if (tid < 72) Rl[tid / 9][tid % 9] = R[rowbase * 9 + tid];
  if (tid >= 72 && tid < 96) { int q = tid - 72; tl[q / 3][q % 3] = t[rowbase * 3 + q]; }
  __syncthreads();

  {
    const float* Ws[3] = {Wq, Wk, Wv};
    float* Os[3] = {qn, kn, vn};
    for (int wmat = 0; wmat < 3; ++wmat) {
      const float* W = Ws[wmat];
      float acc[8];
#pragma unroll
      for (int r = 0; r < 8; ++r) acc[r] = 0.f;
      for (int k = 0; k < 128; ++k) {
        const float w = W[k * 256 + tid];
#pragma unroll
        for (int r = 0; r < 8; ++r) acc[r] = fmaf(xs[r][k], w, acc[r]);
      }
#pragma unroll
      for (int r = 0; r < 8; ++r) Os[wmat][(rowbase + r) * 256 + tid] = acc[r];
    }
  }

  {
    const float* Ws[3] = {Wqp, Wkp, Wvp};
    float* Os[3] = {qp, kp, vp};
    float* O2s[2] = {qp2, kp2};
    for (int wmat = 0; wmat < 3; ++wmat) {
      __syncthreads();
      if (tid < 192) {
        const float* W = Ws[wmat];
        float acc[8];
#pragma unroll
        for (int r = 0; r < 8; ++r) acc[r] = 0.f;
        for (int k = 0; k < 128; ++k) {
          const float w = W[k * 192 + tid];
#pragma unroll
          for (int r = 0; r < 8; ++r) acc[r] = fmaf(xs[r][k], w, acc[r]);
        }
#pragma unroll
        for (int r = 0; r < 8; ++r) plocal[r][tid] = acc[r];
      }
      __syncthreads();
      for (int task = tid; task < 512; task += 256) {
        const int r = task >> 6, hp = task & 63;
        const float px = plocal[r][hp * 3 + 0];
        const float py = plocal[r][hp * 3 + 1];
        const float pz = plocal[r][hp * 3 + 2];
#pragma unroll
        for (int i = 0; i < 3; ++i) {
          const float g = Rl[r][i * 3 + 0] * px + Rl[r][i * 3 + 1] * py +
                          Rl[r][i * 3 + 2] * pz + tl[r][i];
          pglob[r][hp * 3 + i] = g;
          Os[wmat][(rowbase + r) * 192 + hp * 3 + i] = g;
        }
      }
      __syncthreads();
      if (wmat < 2 && tid < 64) {
        const int r = tid >> 3, h = tid & 7;
        float s = 0.f;
#pragma unroll
        for (int j = 0; j < 24; ++j) {
          const float v = pglob[r][h * 24 + j];
          s = fmaf(v, v, s);
        }
        O2s[wmat][(rowbase + r) * 8 + h] = s;
      }
    }
  }
}

// ---------------------------------------------------------------- zw = z @ Wpair
// thread owns 8-p segment x all 8 heads; butterfly-select reduce over 8 lanes.
__global__ __launch_bounds__(256) void zw_kernel(
    const float* __restrict__ z, const float* __restrict__ Wp,
    float* __restrict__ zw) {
  const int tid = threadIdx.x;
  const int r = tid >> 3, pseg = tid & 7;
  float w[8][8];
#pragma unroll
  for (int pp = 0; pp < 8; ++pp) {
    const float4 wa = *(const float4*)&Wp[(pseg * 8 + pp) * 8];
    const float4 wb = *(const float4*)&Wp[(pseg * 8 + pp) * 8 + 4];
    w[pp][0] = wa.x; w[pp][1] = wa.y; w[pp][2] = wa.z; w[pp][3] = wa.w;
    w[pp][4] = wb.x; w[pp][5] = wb.y; w[pp][6] = wb.z; w[pp][7] = wb.w;
  }
  const long base = (long)blockIdx.x * 512;
  for (int it = 0; it < 16; ++it) {
    const long row = base + it * 32 + r;
    const float* zr = &z[row * 64 + pseg * 8];
    const float4 za = *(const float4*)zr;
    const float4 zb = *(const float4*)(zr + 4);
    float a[8];
#pragma unroll
    for (int hh = 0; hh < 8; ++hh) {
      float s = za.x * w[0][hh];
      s = fmaf(za.y, w[1][hh], s);
      s = fmaf(za.z, w[2][hh], s);
      s = fmaf(za.w, w[3][hh], s);
      s = fmaf(zb.x, w[4][hh], s);
      s = fmaf(zb.y, w[5][hh], s);
      s = fmaf(zb.z, w[6][hh], s);
      s = fmaf(zb.w, w[7][hh], s);
      a[hh] = s;
    }
    // butterfly: lane pseg ends with full dot for h = pseg
    float b[4];
#pragma unroll
    for (int j = 0; j < 4; ++j) {
      const float t0 = __shfl_xor(a[j], 4, 64);
      const float t1 = __shfl_xor(a[j + 4], 4, 64);
      b[j] = (pseg & 4) ? (a[j + 4] + t1) : (a[j] + t0);
    }
    float c2[2];
#pragma unroll
    for (int j = 0; j < 2; ++j) {
      const float t0 = __shfl_xor(b[j], 2, 64);
      const float t1 = __shfl_xor(b[j + 2], 2, 64);
      c2[j] = (pseg & 2) ? (b[j + 2] + t1) : (b[j] + t0);
    }
    const float t0 = __shfl_xor(c2[0], 1, 64);
    const float t1 = __shfl_xor(c2[1], 1, 64);
    const float res = (pseg & 1) ? (c2[1] + t1) : (c2[0] + t0);
    zw[row * 8 + pseg] = res;
  }
}

// ---------------------------------------------------------------- flash attention row
__global__ __launch_bounds__(256) void attn_kernel(
    const float* __restrict__ z, const void* __restrict__ intra,
    const void* __restrict__ inter, const int* __restrict__ flag,
    const float* __restrict__ ratio_arr,
    const float* __restrict__ R, const float* __restrict__ t,
    const float* __restrict__ qn, const float* __restrict__ kn,
    const float* __restrict__ vn, const float* __restrict__ qp,
    const float* __restrict__ kp, const float* __restrict__ vp,
    const float* __restrict__ qp2, const float* __restrict__ kp2,
    const float* __restrict__ zw, const float* __restrict__ spatial_coef,
    float* __restrict__ agg) {
  __shared__ float qn_l[8][36];
  __shared__ float qp_l[8][28];
  __shared__ float mI[512], mT[512];
  __shared__ float lgEh[2][8][72];   // e-values [stream][h][mm]
  __shared__ float wredM[2][4][8], wredD[2][4][8];
  __shared__ float MxS[2][8], fac[2][8], Sden[2][8], wfin[2][8];
  __shared__ float qp2_l[8], coef_l[8];
  __shared__ float scratch[2048];
  __shared__ float fsbuf[192];
  __shared__ float Rl[9], tl[3];

  const int tid = threadIdx.x;
  const long row = blockIdx.x;          // = n*512 + l
  const int n = blockIdx.x >> 9;
  const long nbase = (long)n * kL;
  const int mt = *flag;
  const float ratio = ratio_arr[n];
  const int lane = tid & 63, wv = tid >> 6;
  const int h = tid & 7, m0 = tid >> 3;

  // feat roles
  const int offN = tid >> 6, c64 = tid & 63, h_n = c64 >> 3;
  const int offP = tid >> 5, hg = (tid >> 4) & 1, p4 = tid & 15;
  const int offS = tid / 48, ps = tid - offS * 48, h_s = ps / 6;

  // ---- prologue staging ----
  qn_l[tid >> 5][tid & 31] = qn[row * 256 + tid];
  if (tid < 192) qp_l[tid / 24][tid % 24] = qp[row * 192 + tid];
  if (tid < 8) {
    qp2_l[tid] = qp2[row * 8 + tid];
    const float g = logf(1.f + expf(spatial_coef[tid]));
    coef_l[tid] = -g * sqrtf(2.f / (9.f * kNP)) * 0.5f;
  }
  if (tid < 16) { MxS[tid >> 3][tid & 7] = -3.0e38f; Sden[tid >> 3][tid & 7] = 0.f; }
  if (tid < 64) ((float*)wredD)[tid] = 0.f;
  if (tid < 9) Rl[tid] = R[row * 9 + tid];
  if (tid >= 16 && tid < 19) tl[tid - 16] = t[row * 3 + (tid - 16)];
  {
    const long mbase = row * kL;
    for (int m = tid; m < 512; m += 256) {
      mI[m] = mask_at(intra, mbase + m, mt) ? 1.f : 0.f;
      mT[m] = mask_at(inter, mbase + m, mt) ? 1.f : 0.f;
    }
  }
  __syncthreads();

  const float invsC = 0.17677669529663687f;  // 1/sqrt(32)
  const float invs3 = 0.5773502691896258f;   // sqrt(1/3)
  const float q2h = qp2_l[h];
  const float coefh = coef_l[h];

  float4 zero4 = {0.f, 0.f, 0.f, 0.f};
  float4 accN[2] = {zero4, zero4};
  float4 accS[2] = {zero4, zero4};
  float4 accP[2][4];
#pragma unroll
  for (int s = 0; s < 2; ++s)
#pragma unroll
    for (int j = 0; j < 4; ++j) accP[s][j] = zero4;

  for (int c = 0; c < 8; ++c) {
    const int mgb = c * 64;
    // ---- logits for this thread's two m values ----
    float vhalf[2]; bool bI[2], bT[2];
    float mxI = -3.0e38f, mxT = -3.0e38f;
#pragma unroll
    for (int half = 0; half < 2; ++half) {
      const int mm = m0 + 32 * half;
      const int mg = mgb + mm;
      const long krow = nbase + mg;
      float dn = 0.f;
      const float4* knp = (const float4*)&kn[krow * 256 + h * 32];
      const float4* qnp = (const float4*)&qn_l[h][0];
#pragma unroll
      for (int c4 = 0; c4 < 8; ++c4) {
        const float4 kv = knp[c4]; const float4 qv = qnp[c4];
        dn = fmaf(qv.x, kv.x, dn); dn = fmaf(qv.y, kv.y, dn);
        dn = fmaf(qv.z, kv.z, dn); dn = fmaf(qv.w, kv.w, dn);
      }
      float ds = 0.f;
      const float4* kpp = (const float4*)&kp[krow * 192 + h * 24];
      const float4* qpp = (const float4*)&qp_l[h][0];
#pragma unroll
      for (int j4 = 0; j4 < 6; ++j4) {
        const float4 kv = kpp[j4]; const float4 qv = qpp[j4];
        ds = fmaf(qv.x, kv.x, ds); ds = fmaf(qv.y, kv.y, ds);
        ds = fmaf(qv.z, kv.z, ds); ds = fmaf(qv.w, kv.w, ds);
      }
      const float dp = zw[((row << 9) + mg) * 8 + h];
      const float sumsq = q2h + kp2[krow * 8 + h] - 2.f * ds;
      const float v = (dn * invsC + dp + sumsq * coefh) * invs3;
      vhalf[half] = v;
      const bool mi = (mI[mg] != 0.f), mtt = (mT[mg] != 0.f);
      bI[half] = mi; bT[half] = mtt;
      if (mi) mxI = fmaxf(mxI, v);
      if (mtt) mxT = fmaxf(mxT, v);
    }
    // wave max-reduce over the m0 lanes (bits 3..5)
#pragma unroll
    for (int d = 8; d <= 32; d <<= 1) {
      mxI = fmaxf(mxI, __shfl_xor(mxI, d, 64));
      mxT = fmaxf(mxT, __shfl_xor(mxT, d, 64));
    }
    if (lane < 8) { wredM[0][wv][lane] = mxI; wredM[1][wv][lane] = mxT; }
    __syncthreads();   // B1: wredM ready
    if (tid < 16) {
      const int s = tid >> 3, hh = tid & 7;
      const float cm = fmaxf(fmaxf(wredM[s][0][hh], wredM[s][1][hh]),
                             fmaxf(wredM[s][2][hh], wredM[s][3][hh]));
      const float old = MxS[s][hh];
      const float nm = fmaxf(old, cm);
      const float f = __expf(old - nm);
      const float dsum = wredD[s][0][hh] + wredD[s][1][hh] +
                         wredD[s][2][hh] + wredD[s][3][hh];  // prev chunk's denom
      Sden[s][hh] = (Sden[s][hh] + dsum) * f;
      MxS[s][hh] = nm; fac[s][hh] = f;
    }
    __syncthreads();   // B2: MxS/fac ready
    // rescale accumulators
    {
      const float fnI = fac[0][h_n], fnT = fac[1][h_n];
      accN[0].x *= fnI; accN[0].y *= fnI; accN[0].z *= fnI; accN[0].w *= fnI;
      accN[1].x *= fnT; accN[1].y *= fnT; accN[1].z *= fnT; accN[1].w *= fnT;
      const float fsI = fac[0][h_s], fsT = fac[1][h_s];
      accS[0].x *= fsI; accS[0].y *= fsI; accS[0].z *= fsI; accS[0].w *= fsI;
      accS[1].x *= fsT; accS[1].y *= fsT; accS[1].z *= fsT; accS[1].w *= fsT;
#pragma unroll
      for (int j = 0; j < 4; ++j) {
        const float fpI = fac[0][hg * 4 + j], fpT = fac[1][hg * 4 + j];
        accP[0][j].x *= fpI; accP[0][j].y *= fpI; accP[0][j].z *= fpI; accP[0][j].w *= fpI;
        accP[1][j].x *= fpT; accP[1][j].y *= fpT; accP[1][j].z *= fpT; accP[1][j].w *= fpT;
      }
    }
    // e-values + denominators
    {
      float dI = 0.f, dT = 0.f;
      const float MxIh = MxS[0][h], MxTh = MxS[1][h];
#pragma unroll
      for (int half = 0; half < 2; ++half) {
        const int mm = m0 + 32 * half;
        const float eI = bI[half] ? __expf(vhalf[half] - MxIh) : 0.f;
        const float eT = bT[half] ? __expf(vhalf[half] - MxTh) : 0.f;
        lgEh[0][h][mm] = eI; lgEh[1][h][mm] = eT;
        dI += eI; dT += eT;
      }
#pragma unroll
      for (int d = 8; d <= 32; d <<= 1) {
        dI += __shfl_xor(dI, d, 64);
        dT += __shfl_xor(dT, d, 64);
      }
      if (lane < 8) { wredD[0][wv][lane] = dI; wredD[1][wv][lane] = dT; }
    }
    __syncthreads();   // B3: lgEh ready
    // ---- feats ----
    // node: mm = offN*16 + k, col = c64*4
    {
      const long vbase = (nbase + mgb + offN * 16) * 256 + c64 * 4;
#pragma unroll
      for (int q = 0; q < 4; ++q) {
        const float4 eIq = *(const float4*)&lgEh[0][h_n][offN * 16 + q * 4];
        const float4 eTq = *(const float4*)&lgEh[1][h_n][offN * 16 + q * 4];
#define NODE_STEP(kk)                                                        \
        {                                                                    \
          const float4 v4 = *(const float4*)&vn[vbase + (q * 4 + kk) * 256]; \
          const float ei = E4(eIq, kk), et = E4(eTq, kk);                    \
          accN[0].x = fmaf(ei, v4.x, accN[0].x);                             \
          accN[0].y = fmaf(ei, v4.y, accN[0].y);                             \
          accN[0].z = fmaf(ei, v4.z, accN[0].z);                             \
          accN[0].w = fmaf(ei, v4.w, accN[0].w);                             \
          accN[1].x = fmaf(et, v4.x, accN[1].x);                             \
          accN[1].y = fmaf(et, v4.y, accN[1].y);                             \
          accN[1].z = fmaf(et, v4.z, accN[1].z);                             \
          accN[1].w = fmaf(et, v4.w, accN[1].w);                             \
        }
        NODE_STEP(0) NODE_STEP(1) NODE_STEP(2) NODE_STEP(3)
#undef NODE_STEP
      }
    }
    // pair: mm = offP*8 + (0..7), tile 4h x 4p, z from global
    {
      const long zbase = (row * kL + mgb + offP * 8) * 64 + p4 * 4;
#pragma unroll
      for (int half4 = 0; half4 < 2; ++half4) {
        const int mmb = offP * 8 + half4 * 4;
        float4 eIr[4], eTr[4];
#pragma unroll
        for (int j = 0; j < 4; ++j) {
          eIr[j] = *(const float4*)&lgEh[0][hg * 4 + j][mmb];
          eTr[j] = *(const float4*)&lgEh[1][hg * 4 + j][mmb];
        }
#define PAIR_STEP(kk)                                                         \
        {                                                                     \
          const float4 z4 = *(const float4*)&z[zbase + (half4 * 4 + kk) * 64];\
          _Pragma("unroll")                                                   \
          for (int j = 0; j < 4; ++j) {                                       \
            const float ei = E4(eIr[j], kk), et = E4(eTr[j], kk);             \
            accP[0][j].x = fmaf(ei, z4.x, accP[0][j].x);                      \
            accP[0][j].y = fmaf(ei, z4.y, accP[0][j].y);                      \
            accP[0][j].z = fmaf(ei, z4.z, accP[0][j].z);                      \
            accP[0][j].w = fmaf(ei, z4.w, accP[0][j].w);                      \
            accP[1][j].x = fmaf(et, z4.x, accP[1][j].x);                      \
            accP[1][j].y = fmaf(et, z4.y, accP[1][j].y);                      \
            accP[1][j].z = fmaf(et, z4.z, accP[1][j].z);                      \
            accP[1][j].w = fmaf(et, z4.w, accP[1][j].w);                      \
          }                                                                   \
        }
        PAIR_STEP(0) PAIR_STEP(1) PAIR_STEP(2) PAIR_STEP(3)
#undef PAIR_STEP
      }
    }
    // spatial: tid<192, mm = offS*16 + k, col = ps*4
    if (tid < 192) {
      const long pbase = (nbase + mgb + offS * 16) * 192 + ps * 4;
#pragma unroll
      for (int q = 0; q < 4; ++q) {
        const float4 eIq = *(const float4*)&lgEh[0][h_s][offS * 16 + q * 4];
        const float4 eTq = *(const float4*)&lgEh[1][h_s][offS * 16 + q * 4];
#define SPAT_STEP(kk)                                                        \
        {                                                                    \
          const float4 v4 = *(const float4*)&vp[pbase + (q * 4 + kk) * 192]; \
          const float ei = E4(eIq, kk), et = E4(eTq, kk);                    \
          accS[0].x = fmaf(ei, v4.x, accS[0].x);                             \
          accS[0].y = fmaf(ei, v4.y, accS[0].y);                             \
          accS[0].z = fmaf(ei, v4.z, accS[0].z);                             \
          accS[0].w = fmaf(ei, v4.w, accS[0].w);                             \
          accS[1].x = fmaf(et, v4.x, accS[1].x);                             \
          accS[1].y = fmaf(et, v4.y, accS[1].y);                             \
          accS[1].z = fmaf(et, v4.z, accS[1].z);                             \
          accS[1].w = fmaf(et, v4.w, accS[1].w);                             \
        }
        SPAT_STEP(0) SPAT_STEP(1) SPAT_STEP(2) SPAT_STEP(3)
#undef SPAT_STEP
      }
    }
    // no end-of-chunk barrier needed: next writes to lgEh happen after next B2
  }

  // ---- epilogue ----
  if (tid < 16) {  // drain last chunk denoms, final weights
    const int s = tid >> 3, hh = tid & 7;
    const float S = Sden[s][hh] + wredD[s][0][hh] + wredD[s][1][hh] +
                    wredD[s][2][hh] + wredD[s][3][hh];
    const float wsc = (s == 0) ? ratio : (1.f - ratio);
    wfin[s][hh] = (S > 0.f) ? (wsc / S) : 0.f;
  }
  __syncthreads();

  float* aggrow = &agg[row * 832];
  // node reduce: scratch[(offN*2+s)*256 + col]
  *(float4*)&scratch[(offN * 2 + 0) * 256 + c64 * 4] = accN[0];
  *(float4*)&scratch[(offN * 2 + 1) * 256 + c64 * 4] = accN[1];
  __syncthreads();
  {
    const int col = tid, hh = col >> 5;
    const float FI = scratch[col] + scratch[512 + col] + scratch[1024 + col] + scratch[1536 + col];
    const float FT = scratch[256 + col] + scratch[768 + col] + scratch[1280 + col] + scratch[1792 + col];
    aggrow[col] = wfin[0][hh] * FI + wfin[1][hh] * FT;
  }
  __syncthreads();
  // pair: merge offP pairs in-wave, then LDS reduce over 4 waves; stream I then T
#pragma unroll
  for (int s = 0; s < 2; ++s)
#pragma unroll
    for (int j = 0; j < 4; ++j) {
      float4 v = accP[s][j];
      v.x += __shfl_xor(v.x, 32, 64); v.y += __shfl_xor(v.y, 32, 64);
      v.z += __shfl_xor(v.z, 32, 64); v.w += __shfl_xor(v.w, 32, 64);
      accP[s][j] = v;
    }
  float FI0 = 0.f, FI1 = 0.f, FT0 = 0.f, FT1 = 0.f;
  if ((tid & 32) == 0) {
#pragma unroll
    for (int j = 0; j < 4; ++j)
      *(float4*)&scratch[wv * 512 + (hg * 4 + j) * 64 + p4 * 4] = accP[0][j];
  }
  __syncthreads();
  FI0 = scratch[tid] + scratch[512 + tid] + scratch[1024 + tid] + scratch[1536 + tid];
  FI1 = scratch[256 + tid] + scratch[768 + tid] + scratch[1280 + tid] + scratch[1792 + tid];
  __syncthreads();
  if ((tid & 32) == 0) {
#pragma unroll
    for (int j = 0; j < 4; ++j)
      *(float4*)&scratch[wv * 512 + (hg * 4 + j) * 64 + p4 * 4] = accP[1][j];
  }
  __syncthreads();
  FT0 = scratch[tid] + scratch[512 + tid] + scratch[1024 + tid] + scratch[1536 + tid];
  FT1 = scratch[256 + tid] + scratch[768 + tid] + scratch[1280 + tid] + scratch[1792 + tid];
  {
    const int h0 = tid >> 6, h1 = (tid + 256) >> 6;
    aggrow[256 + tid] = wfin[0][h0] * FI0 + wfin[1][h0] * FT0;
    aggrow[512 + tid] = wfin[0][h1] * FI1 + wfin[1][h1] * FT1;
  }
  __syncthreads();
  // spatial reduce: scratch[(offS*2+s)*192 + col]
  if (tid < 192) {
    *(float4*)&scratch[(offS * 2 + 0) * 192 + ps * 4] = accS[0];
    *(float4*)&scratch[(offS * 2 + 1) * 192 + ps * 4] = accS[1];
  }
  __syncthreads();
  if (tid < 192) {
    const float FI = scratch[tid] + scratch[384 + tid] + scratch[768 + tid] + scratch[1152 + tid];
    const float FT = scratch[192 + tid] + scratch[576 + tid] + scratch[960 + tid] + scratch[1344 + tid];
    const int hh = tid / 24;
    fsbuf[tid] = wfin[0][hh] * FI + wfin[1][hh] * FT;
  }
  __syncthreads();
  if (tid < 64) {
    const float gx = fsbuf[tid * 3 + 0] - tl[0];
    const float gy = fsbuf[tid * 3 + 1] - tl[1];
    const float gz = fsbuf[tid * 3 + 2] - tl[2];
    float s = 0.f;
#pragma unroll
    for (int jj = 0; jj < 3; ++jj) {
      const float lv = Rl[0 + jj] * gx + Rl[3 + jj] * gy + Rl[6 + jj] * gz;
      s = fmaf(lv, lv, s);
    }
    aggrow[768 + tid] = sqrtf(s);
  }
}

// ---------------------------------------------------------------- transition / MLP
__device__ __forceinline__ float blk_sum128(float v, float* red, int tid) {
  red[tid] = v; __syncthreads();
  for (int s = 64; s > 0; s >>= 1) {
    if (tid < s) red[tid] += red[tid + s];
    __syncthreads();
  }
  const float r = red[0];
  __syncthreads();
  return r;
}

__global__ __launch_bounds__(128) void trans_kernel(
    const float* __restrict__ xg, const float* __restrict__ agg,
    const float* __restrict__ W1, const float* __restrict__ b1,
    const float* __restrict__ W2a, const float* __restrict__ b2a,
    const float* __restrict__ W2b, const float* __restrict__ b2b,
    const float* __restrict__ W2c, const float* __restrict__ b2c,
    const float* __restrict__ g1, const float* __restrict__ bb1,
    const float* __restrict__ g2, const float* __restrict__ bb2,
    float* __restrict__ out) {
  __shared__ float aggb[832];
  __shared__ float featb[128], hb1[128], hb2[128];
  __shared__ float red[128];
  const int tid = threadIdx.x;
  const long row = blockIdx.x;
  const float* arow = &agg[row * 832];
  for (int i = tid; i < 832; i += 128) aggb[i] = arow[i];
  __syncthreads();
  float acc = b1[tid];
  for (int a = 0; a < 832; ++a) acc = fmaf(aggb[a], W1[a * 128 + tid], acc);
  acc += xg[row * 128 + tid];
  const float mean = blk_sum128(acc, red, tid) * (1.f / 128.f);
  const float dv = acc - mean;
  const float var = blk_sum128(dv * dv, red, tid) * (1.f / 128.f);
  const float f = dv * rsqrtf(var + 1e-5f) * g1[tid] + bb1[tid];
  featb[tid] = f;
  __syncthreads();
  float a1 = b2a[tid];
  for (int k = 0; k < 128; ++k) a1 = fmaf(featb[k], W2a[k * 128 + tid], a1);
  hb1[tid] = fmaxf(a1, 0.f);
  __syncthreads();
  float a2 = b2b[tid];
  for (int k = 0; k < 128; ++k) a2 = fmaf(hb1[k], W2b[k * 128 + tid], a2);
  hb2[tid] = fmaxf(a2, 0.f);
  __syncthreads();
  float a3 = b2c[tid];
  for (int k = 0; k < 128; ++k) a3 = fmaf(hb2[k], W2c[k * 128 + tid], a3);
  const float res = f + a3;
  const float mean2 = blk_sum128(res, red, tid) * (1.f / 128.f);
  const float dv2 = res - mean2;
  const float var2 = blk_sum128(dv2 * dv2, red, tid) * (1.f / 128.f);
  out[row * 128 + tid] = dv2 * rsqrtf(var2 + 1e-5f) * g2[tid] + bb2[tid];
}

// ---------------------------------------------------------------- launch
extern "C" void kernel_launch(void* const* d_in, const int* in_sizes, int n_in,
                              void* d_out, int out_size, void* d_ws, size_t ws_size,
                              hipStream_t stream) {
  const float* R     = (const float*)d_in[0];
  const float* t     = (const float*)d_in[1];
  const float* x     = (const float*)d_in[2];
  const float* z     = (const float*)d_in[3];
  const void*  intra = d_in[4];
  const void*  inter = d_in[5];
  const float* Wq    = (const float*)d_in[6];
  const float* Wk    = (const float*)d_in[7];
  const float* Wv    = (const float*)d_in[8];
  const float* Wpair = (const float*)d_in[9];
  const float* sc    = (const float*)d_in[10];
  const float* Wqp   = (const float*)d_in[11];
  const float* Wkp   = (const float*)d_in[12];
  const float* Wvp   = (const float*)d_in[13];
  const float* W1    = (const float*)d_in[14];
  const float* b1    = (const float*)d_in[15];
  const float* W2a   = (const float*)d_in[16];
  const float* b2a   = (const float*)d_in[17];
  const float* W2b   = (const float*)d_in[18];
  const float* b2b   = (const float*)d_in[19];
  const float* W2c   = (const float*)d_in[20];
  const float* b2c   = (const float*)d_in[21];
  const float* ln1g  = (const float*)d_in[22];
  const float* ln1b  = (const float*)d_in[23];
  const float* ln2g  = (const float*)d_in[24];
  const float* ln2b  = (const float*)d_in[25];
  float* ws = (float*)d_ws;
  float* out = (float*)d_out;

  int* flag = (int*)ws;
  float* ratio = ws + OFF_RATIO;
  float* sums = ws + OFF_SUMS;
  float* qn = ws + OFF_QN;  float* kn = ws + OFF_KN;  float* vn = ws + OFF_VN;
  float* qp = ws + OFF_QP;  float* kp = ws + OFF_KP;  float* vp = ws + OFF_VP;
  float* qp2 = ws + OFF_QP2; float* kp2 = ws + OFF_KP2;
  float* agg = ws + OFF_AGG;
  float* zw  = ws + OFF_ZW;

  detect_mask_type_kernel<<<1, 256, 0, stream>>>((const unsigned int*)intra, flag);
  zero_sums_kernel<<<1, 64, 0, stream>>>(sums);
  mask_ratio_partial_kernel<<<256, 256, 0, stream>>>(intra, inter, flag, sums);
  mask_ratio_final_kernel<<<1, 64, 0, stream>>>(sums, ratio);
  proj_kernel<<<kN * kL / 8, 256, 0, stream>>>(x, R, t, Wq, Wk, Wv, Wqp, Wkp, Wvp,
                                               qn, kn, vn, qp, kp, vp, qp2, kp2);
  zw_kernel<<<2048, 256, 0, stream>>>(z, Wpair, zw);
  attn_kernel<<<kN * kL, 256, 0, stream>>>(z, intra, inter, flag, ratio, R, t,
                                           qn, kn, vn, qp, kp, vp, qp2, kp2,
                                           zw, sc, agg);
  trans_kernel<<<kN * kL, 128, 0, stream>>>(x, agg, W1, b1, W2a, b2a, W2b, b2b,
                                            W2c, b2c, ln1g, ln1b, ln2g, ln2b, out);
}